// Round 9
// baseline (162.412 us; speedup 1.0000x reference)
//
#include <hip/hip_runtime.h>

typedef unsigned short u16;
typedef __attribute__((ext_vector_type(8))) short short8;   // 8 bf16 = 4 VGPRs (MFMA A/B frag)
typedef __attribute__((ext_vector_type(4))) float f32x4;    // MFMA C/D frag

static __device__ __forceinline__ u16 f32_to_bf16(float f) {
  unsigned u = __float_as_uint(f);
  u += 0x7fffu + ((u >> 16) & 1u);   // round-to-nearest-even; inputs finite
  return (u16)(u >> 16);
}

// async global->LDS, 16 B per lane; lds base must be wave-uniform, lane i
// lands at base + i*16 (m97/m104 semantics).
static __device__ __forceinline__ void async16(u16* lds, const u16* g) {
  __builtin_amdgcn_global_load_lds(
      (const __attribute__((address_space(1))) void*)g,
      (__attribute__((address_space(3))) void*)lds, 16, 0, 0);
}

// XOR-swizzled LDS tiles: row r (8 chunks of 16B), logical chunk c at physical
// c ^ (r&7).  Staging lane uses global chunk (lane&7)^(lane>>3); reads XOR the
// chunk index with lo&7.  Conflict-free (verified: 1.35e7 -> 5.4e5).

// ---------------------------------------------------------------------------
// Kernel 0 (merged prep): id<2048 -> fp32->bf16 convert of x (8 elem/thread);
// id>=2048 -> weight transpose+convert.
// ---------------------------------------------------------------------------
__global__ void __launch_bounds__(256) prep_kernel(
    const float* __restrict__ x,
    const float* __restrict__ Wq, const float* __restrict__ Wk,
    const float* __restrict__ Wv, const float* __restrict__ Wo,
    u16* __restrict__ Xb, u16* __restrict__ WqT, u16* __restrict__ WkvT,
    u16* __restrict__ WoT) {
  __shared__ u16 T[64][72];
  int id = blockIdx.x;
  int tid = threadIdx.x;
  if (id < 2048) {                       // convert role
    int base = (id * 256 + tid) * 8;
    float4 a = *(const float4*)&x[base];
    float4 b = *(const float4*)&x[base + 4];
    short8 v;
    v[0] = (short)f32_to_bf16(a.x); v[1] = (short)f32_to_bf16(a.y);
    v[2] = (short)f32_to_bf16(a.z); v[3] = (short)f32_to_bf16(a.w);
    v[4] = (short)f32_to_bf16(b.x); v[5] = (short)f32_to_bf16(b.y);
    v[6] = (short)f32_to_bf16(b.z); v[7] = (short)f32_to_bf16(b.w);
    *(short8*)&Xb[base] = v;
    return;
  }
  int id2 = id - 2048;                   // transpose role, 0..543
  const float* src; u16* dst; int tk, tn, src_ld, row_off;
  if (id2 < 256)      { src = Wq; dst = WqT;  tk = id2 & 15; tn = id2 >> 4; src_ld = 1024; row_off = 0; }
  else if (id2 < 512) { int i = id2 - 256; src = Wo; dst = WoT; tk = i & 15; tn = i >> 4; src_ld = 1024; row_off = 0; }
  else if (id2 < 528) { src = Wk; dst = WkvT; tk = id2 - 512; tn = 0; src_ld = 64; row_off = 0; }
  else                { src = Wv; dst = WkvT; tk = id2 - 528; tn = 0; src_ld = 64; row_off = 64; }
  int k0 = tk * 64, n0 = tn * 64;
#pragma unroll
  for (int it = 0; it < 2; ++it) {
    int c = tid + it * 256;            // 0..511
    int r = c >> 3, cc = (c & 7) * 8;  // src row (k), col chunk (n)
    const float* p = &src[(k0 + r) * src_ld + n0 + cc];
    float4 a = *(const float4*)&p[0];
    float4 b = *(const float4*)&p[4];
    short8 v;
    v[0] = (short)f32_to_bf16(a.x); v[1] = (short)f32_to_bf16(a.y);
    v[2] = (short)f32_to_bf16(a.z); v[3] = (short)f32_to_bf16(a.w);
    v[4] = (short)f32_to_bf16(b.x); v[5] = (short)f32_to_bf16(b.y);
    v[6] = (short)f32_to_bf16(b.z); v[7] = (short)f32_to_bf16(b.w);
    *(short8*)&T[r][cc] = v;
  }
  __syncthreads();
#pragma unroll
  for (int it = 0; it < 2; ++it) {
    int c = tid + it * 256;
    int r = c >> 3, cc = (c & 7) * 8;  // dst row (n), col chunk (k)
    short8 v;
#pragma unroll
    for (int j = 0; j < 8; ++j) v[j] = (short)T[cc + j][r];
    *(short8*)&dst[(row_off + n0 + r) * 1024 + k0 + cc] = v;
  }
}

// ---------------------------------------------------------------------------
// GEMM 64x128 tile, BK=64, 4 waves, double-buffered single-barrier K-loop:
//   stage(buf0); for kt { sync; prefetch(nxt); compute(cur); }
// The barrier's vmcnt(0) drain waits only max(0, DMA - compute).
// ---------------------------------------------------------------------------
__device__ __forceinline__ void stage_64x128(
    const u16* __restrict__ A, const u16* __restrict__ BT, int m0, int K,
    int k0, u16* As, u16* Bs, int w, int lrow, int swz8) {
#pragma unroll
  for (int it = 0; it < 2; ++it) {           // A: 8 chunk-groups (64 rows)
    int W = w * 2 + it;
    async16(As + W * 512, &A[(size_t)(m0 + W * 8 + lrow) * K + k0 + swz8]);
  }
#pragma unroll
  for (int it = 0; it < 4; ++it) {           // B: 16 chunk-groups (128 rows)
    int W = w * 4 + it;
    async16(Bs + W * 512, &BT[(size_t)(W * 8 + lrow) * K + k0 + swz8]);
  }
}

__device__ __forceinline__ void gemm_core_64x128_db(
    const u16* __restrict__ A, const u16* __restrict__ BT, int m0, int K,
    f32x4 (&acc)[2][4], u16* As, u16* Bs,   // As: 2 x 64*64, Bs: 2 x 128*64
    int lane, int w, int wr, int wc, int g, int lo) {
  int lrow = lane >> 3;
  int swz8 = ((lane & 7) ^ lrow) * 8;
  int lo7 = lo & 7;
  const int NK = K >> 6;
  stage_64x128(A, BT, m0, K, 0, As, Bs, w, lrow, swz8);
  for (int kt = 0; kt < NK; ++kt) {
    int cur = kt & 1;
    __syncthreads();                         // cur buf ready; nxt buf free
    if (kt + 1 < NK)
      stage_64x128(A, BT, m0, K, (kt + 1) * 64,
                   As + (cur ^ 1) * 4096, Bs + (cur ^ 1) * 8192, w, lrow, swz8);
    const u16* Asc = As + cur * 4096;
    const u16* Bsc = Bs + cur * 8192;
#pragma unroll
    for (int ks = 0; ks < 2; ++ks) {
      int pc = ((ks * 4 + g) ^ lo7) * 8;     // physical chunk offset
      short8 af[2], bf[4];
#pragma unroll
      for (int i = 0; i < 2; ++i)
        af[i] = *(const short8*)&Asc[(wr * 32 + i * 16 + lo) * 64 + pc];
#pragma unroll
      for (int i = 0; i < 4; ++i)
        bf[i] = *(const short8*)&Bsc[(wc * 64 + i * 16 + lo) * 64 + pc];
#pragma unroll
      for (int mi = 0; mi < 2; ++mi)
#pragma unroll
        for (int ni = 0; ni < 4; ++ni)
          acc[mi][ni] = __builtin_amdgcn_mfma_f32_16x16x32_bf16(
              af[mi], bf[ni], acc[mi][ni], 0, 0, 0);
    }
  }
}

// ---------------------------------------------------------------------------
// Kernel 2: QKV projection.  Linear grid 576; XCD-aware m-clustered swizzle:
// xcd = id&7, j = id>>3; m_tile = xcd*8 + (j&7), nb = j>>3.  nb<8: Q tile into
// Qb [4096][1024] (UNSCALED; Qb = d_out scratch).  nb==8: K into KVb
// [4096][64] compact; V transposed into VTb [2][64][2048] (uint2 stores:
// r-consecutive acc values are s-consecutive).
// ---------------------------------------------------------------------------
__global__ void __launch_bounds__(256) qkv_gemm(
    const u16* __restrict__ Xb, const u16* __restrict__ WqT,
    const u16* __restrict__ WkvT, u16* __restrict__ Qb, u16* __restrict__ KVb,
    u16* __restrict__ VTb) {
  __shared__ u16 As[2 * 64 * 64];
  __shared__ u16 Bs[2 * 128 * 64];
  int tid = threadIdx.x, lane = tid & 63, w = tid >> 6;
  int wr = w >> 1, wc = w & 1, g = lane >> 4, lo = lane & 15;
  int id = blockIdx.x;
  int xcd = id & 7, j = id >> 3;
  int m0 = (xcd * 8 + (j & 7)) * 64;
  int nb = j >> 3;                          // 0..8
  const u16* BT = (nb < 8) ? (WqT + (size_t)nb * 128 * 1024) : WkvT;
  f32x4 acc[2][4];
  f32x4 zz = {0.f, 0.f, 0.f, 0.f};
#pragma unroll
  for (int i = 0; i < 2; ++i)
#pragma unroll
    for (int jj = 0; jj < 4; ++jj) acc[i][jj] = zz;
  gemm_core_64x128_db(Xb, BT, m0, 1024, acc, As, Bs, lane, w, wr, wc, g, lo);
  if (nb < 8 || wc == 0) {
#pragma unroll
    for (int mi = 0; mi < 2; ++mi)
#pragma unroll
      for (int ni = 0; ni < 4; ++ni)
#pragma unroll
        for (int r = 0; r < 4; ++r) {
          int row = m0 + wr * 32 + mi * 16 + g * 4 + r;
          int col = wc * 64 + ni * 16 + lo;
          u16 v = f32_to_bf16(acc[mi][ni][r]);
          if (nb < 8) Qb[row * 1024 + nb * 128 + col] = v;
          else        KVb[row * 64 + col] = v;       // K half, compact stride 64
        }
  } else {
    // V: transposed store, 8B vectors (4 s-consecutive bf16 per store)
#pragma unroll
    for (int mi = 0; mi < 2; ++mi)
#pragma unroll
      for (int ni = 0; ni < 4; ++ni) {
        int d = ni * 16 + lo;                        // col - 64
        int row0 = m0 + wr * 32 + mi * 16 + g * 4;   // 4-aligned, same b for r<4
        uint2 pv;
        pv.x = (unsigned)f32_to_bf16(acc[mi][ni][0]) |
               ((unsigned)f32_to_bf16(acc[mi][ni][1]) << 16);
        pv.y = (unsigned)f32_to_bf16(acc[mi][ni][2]) |
               ((unsigned)f32_to_bf16(acc[mi][ni][3]) << 16);
        *(uint2*)&VTb[(((size_t)(row0 >> 11) * 64) + d) * 2048 + (row0 & 2047)] = pv;
      }
  }
}

// ---------------------------------------------------------------------------
// Kernel 3: fused causal flash attention (MQA), paired q-tiles, per-strip Ps,
// R9: PV software-pipelined by one tile.  Iteration t: QK(t); PV(t-1); SM(t).
// QK(t) and PV(t-1) are independent MFMA clusters -> matrix pipe sees them
// back-to-back; SM's exp2 chain feeds PV only one iteration later.
// Buffering: V triple-buffered (stage(t+1) writes (t+1)%3, PV(t-1) reads
// (t-1)%3, distance 2 mod 3; barrier lgkm-drain retires PV(t-2) first).
// Ps depth-2 per strip (SM writes parity t&1, PV reads (t-1)&1; threadfence
// orders across iterations).  lo strip's final PV(a) drains in-loop at t=a+1
// (a+1 <= hi always); epilogue drains PV_hi(nst-1) only.
// LDS = 16384(K) + 24576(V) + 36864(Ps) = 77824 B -> 2 blocks/CU.
// grid (16 pg, 16 h, 2 z) = 512; a = z ? 15-pg : pg (complementary pairs).
// Fixed-offset softmax p = exp2(s*0.125*log2e - 11.5416); l via ones-MFMA.
// ---------------------------------------------------------------------------
__global__ void __launch_bounds__(256, 2) attn_kernel(
    const u16* __restrict__ Qb, const u16* __restrict__ KVb,
    const u16* __restrict__ VTb, u16* __restrict__ AOb) {
  __shared__ u16 Ks[2][64 * 64];       // K tile [key][d], swizzled
  __shared__ u16 Vt[3][64 * 64];       // V tile [d][key], swizzled, 3-deep
  __shared__ u16 Ps[4][2][2][16][72];  // [wave][strip][depth][q][key]
  int tid = threadIdx.x, lane = tid & 63, w = tid >> 6;
  int gq = lane >> 4, lo = lane & 15;
  int pg = blockIdx.x;                      // pair index 0..15
  int h = blockIdx.y;
  int z = blockIdx.z;
  int b = z;
  int a = z ? (15 - pg) : pg;               // lo strip q-tile
  int hi = 31 - a;                          // hi strip q-tile
  int qb_lo = a * 64 + w * 16;              // wave's first q-row, lo strip
  int qb_hi = hi * 64 + w * 16;
  int lrow = lane >> 3;
  int swz8 = ((lane & 7) ^ lrow) * 8;
  int lo7 = lo & 7;

  // Q fragments (A-layout): row = lo, k = ks*32 + gq*8 + j
  short8 qf_lo[2], qf_hi[2];
  {
    const u16* qp = &Qb[(size_t)(b * 2048 + qb_lo + lo) * 1024 + h * 64];
    qf_lo[0] = *(const short8*)&qp[gq * 8];
    qf_lo[1] = *(const short8*)&qp[32 + gq * 8];
    const u16* qp2 = &Qb[(size_t)(b * 2048 + qb_hi + lo) * 1024 + h * 64];
    qf_hi[0] = *(const short8*)&qp2[gq * 8];
    qf_hi[1] = *(const short8*)&qp2[32 + gq * 8];
  }

  short8 ones;
#pragma unroll
  for (int j = 0; j < 8; ++j) ones[j] = (short)0x3F80;  // bf16 1.0

  f32x4 zz = {0.f, 0.f, 0.f, 0.f};
  f32x4 oacc_lo[4], oacc_hi[4], l_lo, l_hi;
#pragma unroll
  for (int i = 0; i < 4; ++i) { oacc_lo[i] = zz; oacc_hi[i] = zz; }
  l_lo = zz; l_hi = zz;

  const float kExp = 0.18033688011112042f;   // 0.125*log2(e)
  const float kOff = 11.541560327111707f;    // 8*log2(e) fixed offset

  // phase pieces -------------------------------------------------------------
  auto qk_phase = [&](const short8 (&qf)[2], f32x4 (&sacc)[4], const u16* Kc) {
#pragma unroll
    for (int ks = 0; ks < 2; ++ks) {
      int pc = ((ks * 4 + gq) ^ lo7) * 8;
      short8 kf[4];
#pragma unroll
      for (int ns = 0; ns < 4; ++ns)
        kf[ns] = *(const short8*)&Kc[(ns * 16 + lo) * 64 + pc];
#pragma unroll
      for (int ns = 0; ns < 4; ++ns)
        sacc[ns] = __builtin_amdgcn_mfma_f32_16x16x32_bf16(
            qf[ks], kf[ns], sacc[ns], 0, 0, 0);
    }
  };
  auto sm_phase = [&](f32x4 (&sacc)[4], int qbase, bool diag, int k0, u16* ps) {
#pragma unroll
    for (int ns = 0; ns < 4; ++ns)
#pragma unroll
      for (int r = 0; r < 4; ++r) {
        float p = __builtin_amdgcn_exp2f(fmaf(sacc[ns][r], kExp, -kOff));
        if (diag) {
          int qg = qbase + gq * 4 + r;
          int kg = k0 + ns * 16 + lo;
          if (kg > qg) p = 0.f;
        }
        ps[(gq * 4 + r) * 72 + ns * 16 + lo] = (u16)(__float_as_uint(p) >> 16);
      }
  };
  auto pv_phase = [&](f32x4 (&oacc)[4], f32x4& l_acc, const u16* ps,
                      const u16* Vc) {
#pragma unroll
    for (int k2 = 0; k2 < 2; ++k2) {
      short8 pf = *(const short8*)&ps[lo * 72 + k2 * 32 + gq * 8];
      int pc = ((k2 * 4 + gq) ^ lo7) * 8;
      short8 vf[4];
#pragma unroll
      for (int ds = 0; ds < 4; ++ds)
        vf[ds] = *(const short8*)&Vc[(ds * 16 + lo) * 64 + pc];
#pragma unroll
      for (int ds = 0; ds < 4; ++ds)
        oacc[ds] = __builtin_amdgcn_mfma_f32_16x16x32_bf16(
            pf, vf[ds], oacc[ds], 0, 0, 0);
      l_acc = __builtin_amdgcn_mfma_f32_16x16x32_bf16(pf, ones, l_acc, 0, 0, 0);
    }
  };

  // stage tile t: K into buffer t&1, V into buffer t%3
  auto stage_kv = [&](int t) {
    int kb = t & 1, vb = t % 3;
#pragma unroll
    for (int it = 0; it < 2; ++it) {
      int W = w * 2 + it;
      async16(&Ks[kb][W * 512],
              &KVb[(size_t)(b * 2048 + t * 64 + W * 8 + lrow) * 64 + swz8]);
      async16(&Vt[vb][W * 512],
              &VTb[((size_t)b * 64 + W * 8 + lrow) * 2048 + t * 64 + swz8]);
    }
  };

  int nst = hi + 1;   // staged tiles: keys 0 .. hi*64+63
  stage_kv(0);
  for (int t = 0; t < nst; ++t) {
    __syncthreads();                 // tile t staged; t+1 buffers free
    if (t + 1 < nst) stage_kv(t + 1);
    int k0 = t * 64;
    bool lo_on = (t <= a);

    f32x4 sacc_hi[4], sacc_lo[4];
#pragma unroll
    for (int ns = 0; ns < 4; ++ns) { sacc_hi[ns] = zz; sacc_lo[ns] = zz; }

    qk_phase(qf_hi, sacc_hi, Ks[t & 1]);
    if (lo_on) qk_phase(qf_lo, sacc_lo, Ks[t & 1]);

    if (t > 0) {                     // drain PV(t-1): independent of QK(t)
      const u16* Vp = Vt[(t - 1) % 3];
      int pp = (t - 1) & 1;
      pv_phase(oacc_hi, l_hi, &Ps[w][0][pp][0][0], Vp);
      if (t - 1 <= a) pv_phase(oacc_lo, l_lo, &Ps[w][1][pp][0][0], Vp);
    }

    sm_phase(sacc_hi, qb_hi, t == hi, k0, &Ps[w][0][t & 1][0][0]);
    if (lo_on) sm_phase(sacc_lo, qb_lo, t == a, k0, &Ps[w][1][t & 1][0][0]);
    __threadfence_block();           // ps writes visible to next iter's PV
  }
  {                                  // epilogue: drain PV_hi(nst-1)
    int t = nst - 1;
    pv_phase(oacc_hi, l_hi, &Ps[w][0][t & 1][0][0], Vt[t % 3]);
  }

  // epilogue: normalize and store [s][h*64+d] bf16, both strips
#pragma unroll
  for (int r = 0; r < 4; ++r) {
    float inv_lo = 1.0f / l_lo[r];
    float inv_hi = 1.0f / l_hi[r];
    int row_lo = b * 2048 + qb_lo + gq * 4 + r;
    int row_hi = b * 2048 + qb_hi + gq * 4 + r;
#pragma unroll
    for (int ds = 0; ds < 4; ++ds) {
      AOb[row_lo * 1024 + h * 64 + ds * 16 + lo] = f32_to_bf16(oacc_lo[ds][r] * inv_lo);
      AOb[row_hi * 1024 + h * 64 + ds * 16 + lo] = f32_to_bf16(oacc_hi[ds][r] * inv_hi);
    }
  }
}

// ---------------------------------------------------------------------------
// Kernel 4: output projection with fp32 bias, fp32 output.  Linear grid 512,
// same XCD-aware m-clustered swizzle as qkv (nb = j>>3 in 0..7).
// ---------------------------------------------------------------------------
__global__ void __launch_bounds__(256) out_gemm(
    const u16* __restrict__ A, const u16* __restrict__ WoT,
    const float* __restrict__ bias, float* __restrict__ C) {
  __shared__ u16 As[2 * 64 * 64];
  __shared__ u16 Bs[2 * 128 * 64];
  int tid = threadIdx.x, lane = tid & 63, w = tid >> 6;
  int wr = w >> 1, wc = w & 1, g = lane >> 4, lo = lane & 15;
  int id = blockIdx.x;
  int xcd = id & 7, j = id >> 3;
  int m0 = (xcd * 8 + (j & 7)) * 64;
  int nb = j >> 3;                          // 0..7
  const u16* BT = WoT + (size_t)nb * 128 * 1024;
  f32x4 acc[2][4];
  f32x4 zz = {0.f, 0.f, 0.f, 0.f};
#pragma unroll
  for (int i = 0; i < 2; ++i)
#pragma unroll
    for (int jj = 0; jj < 4; ++jj) acc[i][jj] = zz;
  gemm_core_64x128_db(A, BT, m0, 1024, acc, As, Bs, lane, w, wr, wc, g, lo);
#pragma unroll
  for (int mi = 0; mi < 2; ++mi)
#pragma unroll
    for (int ni = 0; ni < 4; ++ni)
#pragma unroll
      for (int r = 0; r < 4; ++r) {
        int row = m0 + wr * 32 + mi * 16 + g * 4 + r;
        int col = nb * 128 + wc * 64 + ni * 16 + lo;
        C[row * 1024 + col] = acc[mi][ni][r] + bias[col];
      }
}

// ---------------------------------------------------------------------------
extern "C" void kernel_launch(void* const* d_in, const int* in_sizes, int n_in,
                              void* d_out, int out_size, void* d_ws, size_t ws_size,
                              hipStream_t stream) {
  const float* x  = (const float*)d_in[0];
  const float* Wq = (const float*)d_in[1];
  const float* Wk = (const float*)d_in[2];
  const float* Wv = (const float*)d_in[3];
  const float* Wo = (const float*)d_in[4];
  const float* bo = (const float*)d_in[5];
  float* out = (float*)d_out;

  // bf16 Q scratch lives in d_out (fp32 16.8 MB; Q needs 8 MB, dead before
  // out_gemm overwrites).  ws: AOb | KVb | VTb | Xb | WqT | WoT | WkvT ~21 MB
  u16* ws   = (u16*)d_ws;
  u16* AOb  = ws;                    // 4096*1024
  u16* KVb  = AOb + 4194304;         // 4096*64   (K only, compact)
  u16* VTb  = KVb + 262144;          // 2*64*2048 (V transposed)
  u16* Xb   = VTb + 262144;          // 4096*1024
  u16* WqT  = Xb + 4194304;          // 1024*1024
  u16* WoT  = WqT + 1048576;         // 1024*1024
  u16* WkvT = WoT + 1048576;         // 128*1024
  u16* Qb   = (u16*)d_out;           // 4096*1024 bf16 (scratch phase)

  prep_kernel<<<2592, 256, 0, stream>>>(x, Wq, Wk, Wv, Wo, Xb, WqT, WkvT, WoT);
  qkv_gemm<<<576, 256, 0, stream>>>(Xb, WqT, WkvT, Qb, KVb, VTb);
  attn_kernel<<<dim3(16, 16, 2), 256, 0, stream>>>(Qb, KVb, VTb, AOb);
  out_gemm<<<512, 256, 0, stream>>>(AOb, WoT, bo, out);
}

// Round 10
// 153.915 us; speedup vs baseline: 1.0552x; 1.0552x over previous
//
#include <hip/hip_runtime.h>

typedef unsigned short u16;
typedef __attribute__((ext_vector_type(8))) short short8;   // 8 bf16 = 4 VGPRs (MFMA A/B frag)
typedef __attribute__((ext_vector_type(4))) float f32x4;    // MFMA C/D frag

static __device__ __forceinline__ u16 f32_to_bf16(float f) {
  unsigned u = __float_as_uint(f);
  u += 0x7fffu + ((u >> 16) & 1u);   // round-to-nearest-even; inputs finite
  return (u16)(u >> 16);
}

// async global->LDS, 16 B per lane; lds base must be wave-uniform, lane i
// lands at base + i*16 (m97/m104 semantics).
static __device__ __forceinline__ void async16(u16* lds, const u16* g) {
  __builtin_amdgcn_global_load_lds(
      (const __attribute__((address_space(1))) void*)g,
      (__attribute__((address_space(3))) void*)lds, 16, 0, 0);
}

// XOR-swizzled LDS tiles: row r (8 chunks of 16B), logical chunk c at physical
// c ^ (r&7).  Staging lane uses global chunk (lane&7)^(lane>>3); reads XOR the
// chunk index with lo&7.  Conflict-free (verified: 1.35e7 -> 5.4e5).

// ---------------------------------------------------------------------------
// Kernel 0 (merged prep): id<2048 -> fp32->bf16 convert of x (8 elem/thread);
// id>=2048 -> weight transpose+convert.
// ---------------------------------------------------------------------------
__global__ void __launch_bounds__(256) prep_kernel(
    const float* __restrict__ x,
    const float* __restrict__ Wq, const float* __restrict__ Wk,
    const float* __restrict__ Wv, const float* __restrict__ Wo,
    u16* __restrict__ Xb, u16* __restrict__ WqT, u16* __restrict__ WkvT,
    u16* __restrict__ WoT) {
  __shared__ u16 T[64][72];
  int id = blockIdx.x;
  int tid = threadIdx.x;
  if (id < 2048) {                       // convert role
    int base = (id * 256 + tid) * 8;
    float4 a = *(const float4*)&x[base];
    float4 b = *(const float4*)&x[base + 4];
    short8 v;
    v[0] = (short)f32_to_bf16(a.x); v[1] = (short)f32_to_bf16(a.y);
    v[2] = (short)f32_to_bf16(a.z); v[3] = (short)f32_to_bf16(a.w);
    v[4] = (short)f32_to_bf16(b.x); v[5] = (short)f32_to_bf16(b.y);
    v[6] = (short)f32_to_bf16(b.z); v[7] = (short)f32_to_bf16(b.w);
    *(short8*)&Xb[base] = v;
    return;
  }
  int id2 = id - 2048;                   // transpose role, 0..543
  const float* src; u16* dst; int tk, tn, src_ld, row_off;
  if (id2 < 256)      { src = Wq; dst = WqT;  tk = id2 & 15; tn = id2 >> 4; src_ld = 1024; row_off = 0; }
  else if (id2 < 512) { int i = id2 - 256; src = Wo; dst = WoT; tk = i & 15; tn = i >> 4; src_ld = 1024; row_off = 0; }
  else if (id2 < 528) { src = Wk; dst = WkvT; tk = id2 - 512; tn = 0; src_ld = 64; row_off = 0; }
  else                { src = Wv; dst = WkvT; tk = id2 - 528; tn = 0; src_ld = 64; row_off = 64; }
  int k0 = tk * 64, n0 = tn * 64;
#pragma unroll
  for (int it = 0; it < 2; ++it) {
    int c = tid + it * 256;            // 0..511
    int r = c >> 3, cc = (c & 7) * 8;  // src row (k), col chunk (n)
    const float* p = &src[(k0 + r) * src_ld + n0 + cc];
    float4 a = *(const float4*)&p[0];
    float4 b = *(const float4*)&p[4];
    short8 v;
    v[0] = (short)f32_to_bf16(a.x); v[1] = (short)f32_to_bf16(a.y);
    v[2] = (short)f32_to_bf16(a.z); v[3] = (short)f32_to_bf16(a.w);
    v[4] = (short)f32_to_bf16(b.x); v[5] = (short)f32_to_bf16(b.y);
    v[6] = (short)f32_to_bf16(b.z); v[7] = (short)f32_to_bf16(b.w);
    *(short8*)&T[r][cc] = v;
  }
  __syncthreads();
#pragma unroll
  for (int it = 0; it < 2; ++it) {
    int c = tid + it * 256;
    int r = c >> 3, cc = (c & 7) * 8;  // dst row (n), col chunk (k)
    short8 v;
#pragma unroll
    for (int j = 0; j < 8; ++j) v[j] = (short)T[cc + j][r];
    *(short8*)&dst[(row_off + n0 + r) * 1024 + k0 + cc] = v;
  }
}

// ---------------------------------------------------------------------------
// GEMM 64x128 tile, BK=64, 4 waves, double-buffered single-barrier K-loop:
//   stage(buf0); for kt { sync; prefetch(nxt); compute(cur); }
// The barrier's vmcnt(0) drain waits only max(0, DMA - compute).
// ---------------------------------------------------------------------------
__device__ __forceinline__ void stage_64x128(
    const u16* __restrict__ A, const u16* __restrict__ BT, int m0, int K,
    int k0, u16* As, u16* Bs, int w, int lrow, int swz8) {
#pragma unroll
  for (int it = 0; it < 2; ++it) {           // A: 8 chunk-groups (64 rows)
    int W = w * 2 + it;
    async16(As + W * 512, &A[(size_t)(m0 + W * 8 + lrow) * K + k0 + swz8]);
  }
#pragma unroll
  for (int it = 0; it < 4; ++it) {           // B: 16 chunk-groups (128 rows)
    int W = w * 4 + it;
    async16(Bs + W * 512, &BT[(size_t)(W * 8 + lrow) * K + k0 + swz8]);
  }
}

__device__ __forceinline__ void gemm_core_64x128_db(
    const u16* __restrict__ A, const u16* __restrict__ BT, int m0, int K,
    f32x4 (&acc)[2][4], u16* As, u16* Bs,   // As: 2 x 64*64, Bs: 2 x 128*64
    int lane, int w, int wr, int wc, int g, int lo) {
  int lrow = lane >> 3;
  int swz8 = ((lane & 7) ^ lrow) * 8;
  int lo7 = lo & 7;
  const int NK = K >> 6;
  stage_64x128(A, BT, m0, K, 0, As, Bs, w, lrow, swz8);
  for (int kt = 0; kt < NK; ++kt) {
    int cur = kt & 1;
    __syncthreads();                         // cur buf ready; nxt buf free
    if (kt + 1 < NK)
      stage_64x128(A, BT, m0, K, (kt + 1) * 64,
                   As + (cur ^ 1) * 4096, Bs + (cur ^ 1) * 8192, w, lrow, swz8);
    const u16* Asc = As + cur * 4096;
    const u16* Bsc = Bs + cur * 8192;
#pragma unroll
    for (int ks = 0; ks < 2; ++ks) {
      int pc = ((ks * 4 + g) ^ lo7) * 8;     // physical chunk offset
      short8 af[2], bf[4];
#pragma unroll
      for (int i = 0; i < 2; ++i)
        af[i] = *(const short8*)&Asc[(wr * 32 + i * 16 + lo) * 64 + pc];
#pragma unroll
      for (int i = 0; i < 4; ++i)
        bf[i] = *(const short8*)&Bsc[(wc * 64 + i * 16 + lo) * 64 + pc];
#pragma unroll
      for (int mi = 0; mi < 2; ++mi)
#pragma unroll
        for (int ni = 0; ni < 4; ++ni)
          acc[mi][ni] = __builtin_amdgcn_mfma_f32_16x16x32_bf16(
              af[mi], bf[ni], acc[mi][ni], 0, 0, 0);
    }
  }
}

// ---------------------------------------------------------------------------
// Kernel 2: QKV projection.  Linear grid 576; XCD-aware m-clustered swizzle:
// xcd = id&7, j = id>>3; m_tile = xcd*8 + (j&7), nb = j>>3.  nb<8: Q tile into
// Qb [4096][1024] (UNSCALED; Qb = d_out scratch).  nb==8: K into KVb
// [4096][64] compact; V transposed into VTb [2][64][2048] (uint2 stores).
// ---------------------------------------------------------------------------
__global__ void __launch_bounds__(256) qkv_gemm(
    const u16* __restrict__ Xb, const u16* __restrict__ WqT,
    const u16* __restrict__ WkvT, u16* __restrict__ Qb, u16* __restrict__ KVb,
    u16* __restrict__ VTb) {
  __shared__ u16 As[2 * 64 * 64];
  __shared__ u16 Bs[2 * 128 * 64];
  int tid = threadIdx.x, lane = tid & 63, w = tid >> 6;
  int wr = w >> 1, wc = w & 1, g = lane >> 4, lo = lane & 15;
  int id = blockIdx.x;
  int xcd = id & 7, j = id >> 3;
  int m0 = (xcd * 8 + (j & 7)) * 64;
  int nb = j >> 3;                          // 0..8
  const u16* BT = (nb < 8) ? (WqT + (size_t)nb * 128 * 1024) : WkvT;
  f32x4 acc[2][4];
  f32x4 zz = {0.f, 0.f, 0.f, 0.f};
#pragma unroll
  for (int i = 0; i < 2; ++i)
#pragma unroll
    for (int jj = 0; jj < 4; ++jj) acc[i][jj] = zz;
  gemm_core_64x128_db(Xb, BT, m0, 1024, acc, As, Bs, lane, w, wr, wc, g, lo);
  if (nb < 8 || wc == 0) {
#pragma unroll
    for (int mi = 0; mi < 2; ++mi)
#pragma unroll
      for (int ni = 0; ni < 4; ++ni)
#pragma unroll
        for (int r = 0; r < 4; ++r) {
          int row = m0 + wr * 32 + mi * 16 + g * 4 + r;
          int col = wc * 64 + ni * 16 + lo;
          u16 v = f32_to_bf16(acc[mi][ni][r]);
          if (nb < 8) Qb[row * 1024 + nb * 128 + col] = v;
          else        KVb[row * 64 + col] = v;       // K half, compact stride 64
        }
  } else {
    // V: transposed store, 8B vectors (4 s-consecutive bf16 per store)
#pragma unroll
    for (int mi = 0; mi < 2; ++mi)
#pragma unroll
      for (int ni = 0; ni < 4; ++ni) {
        int d = ni * 16 + lo;                        // col - 64
        int row0 = m0 + wr * 32 + mi * 16 + g * 4;   // 4-aligned, same b for r<4
        uint2 pv;
        pv.x = (unsigned)f32_to_bf16(acc[mi][ni][0]) |
               ((unsigned)f32_to_bf16(acc[mi][ni][1]) << 16);
        pv.y = (unsigned)f32_to_bf16(acc[mi][ni][2]) |
               ((unsigned)f32_to_bf16(acc[mi][ni][3]) << 16);
        *(uint2*)&VTb[(((size_t)(row0 >> 11) * 64) + d) * 2048 + (row0 & 2047)] = pv;
      }
  }
}

// ---------------------------------------------------------------------------
// Kernel 3: fused causal flash attention (MQA), paired q-tiles, R10: 8-wave
// split-key.  512-thread blocks; wave w owns q-chunk qc=w&3 and key-half
// h2=w>>2 (32 of the 64 keys per tile).  Same total work/staging as R0/R8;
// per-wave serial chain HALVES (4 QK MFMA + 8 exp2 + 4 PV MFMA + 1 l-MFMA),
// waves/SIMD doubles (2 blocks/CU x 8 waves = 4/SIMD).  O,l are partial sums
// over key halves (linear) -> waves (w, w+4) combine once at epilogue via
// LDS scratch (Ks/Vt reused post-loop; l partials via Ps).
// grid (16 pg, 16 h, 2 z) = 512; a = z ? 15-pg : pg (complementary pairs).
// LDS = 16384(K) + 16384(V) + 20480(Ps) = 53248 B -> 2 blocks/CU.
// Fixed-offset softmax p = exp2(s*0.125*log2e - 11.5416); l via ones-MFMA.
// ---------------------------------------------------------------------------
__global__ void __launch_bounds__(512, 4) attn_kernel(
    const u16* __restrict__ Qb, const u16* __restrict__ KVb,
    const u16* __restrict__ VTb, u16* __restrict__ AOb) {
  __shared__ u16 Ks[2][64 * 64];     // K tile [key][d], swizzled
  __shared__ u16 Vt[2][64 * 64];     // V tile [d][key], swizzled
  __shared__ u16 Ps[8][2][16][40];   // per-wave per-strip P [q][key-half], pad 40
  int tid = threadIdx.x, lane = tid & 63, w = tid >> 6;   // w: 0..7
  int qc = w & 3;                    // q-chunk
  int h2 = w >> 2;                   // key half (0: keys 0-31, 1: keys 32-63)
  int gq = lane >> 4, lo = lane & 15;
  int pg = blockIdx.x;               // pair index 0..15
  int h = blockIdx.y;
  int z = blockIdx.z;
  int b = z;
  int a = z ? (15 - pg) : pg;        // lo strip q-tile
  int hi = 31 - a;                   // hi strip q-tile
  int qb_lo = a * 64 + qc * 16;      // wave's first q-row, lo strip
  int qb_hi = hi * 64 + qc * 16;
  int lrow = lane >> 3;
  int swz8 = ((lane & 7) ^ lrow) * 8;
  int lo7 = lo & 15 & 7;

  // Q fragments (A-layout): row = lo, k = ks*32 + gq*8 + j
  short8 qf_lo[2], qf_hi[2];
  {
    const u16* qp = &Qb[(size_t)(b * 2048 + qb_lo + lo) * 1024 + h * 64];
    qf_lo[0] = *(const short8*)&qp[gq * 8];
    qf_lo[1] = *(const short8*)&qp[32 + gq * 8];
    const u16* qp2 = &Qb[(size_t)(b * 2048 + qb_hi + lo) * 1024 + h * 64];
    qf_hi[0] = *(const short8*)&qp2[gq * 8];
    qf_hi[1] = *(const short8*)&qp2[32 + gq * 8];
  }

  short8 ones;
#pragma unroll
  for (int j = 0; j < 8; ++j) ones[j] = (short)0x3F80;  // bf16 1.0

  f32x4 zz = {0.f, 0.f, 0.f, 0.f};
  f32x4 oacc_lo[4], oacc_hi[4], l_lo, l_hi;   // PARTIAL over this key half
#pragma unroll
  for (int i = 0; i < 4; ++i) { oacc_lo[i] = zz; oacc_hi[i] = zz; }
  l_lo = zz; l_hi = zz;

  const float kExp = 0.18033688011112042f;   // 0.125*log2(e)
  const float kOff = 11.541560327111707f;    // 8*log2(e) fixed offset

  // phase pieces (this wave's 32-key half) ----------------------------------
  auto qk_phase = [&](const short8 (&qf)[2], f32x4 (&sacc)[2], const u16* Kc) {
#pragma unroll
    for (int ks = 0; ks < 2; ++ks) {
      int pc = ((ks * 4 + gq) ^ lo7) * 8;
      short8 kf[2];
#pragma unroll
      for (int ns = 0; ns < 2; ++ns)
        kf[ns] = *(const short8*)&Kc[(h2 * 32 + ns * 16 + lo) * 64 + pc];
#pragma unroll
      for (int ns = 0; ns < 2; ++ns)
        sacc[ns] = __builtin_amdgcn_mfma_f32_16x16x32_bf16(
            qf[ks], kf[ns], sacc[ns], 0, 0, 0);
    }
  };
  auto sm_phase = [&](f32x4 (&sacc)[2], int qbase, bool diag, int k0, u16* ps) {
#pragma unroll
    for (int ns = 0; ns < 2; ++ns)
#pragma unroll
      for (int r = 0; r < 4; ++r) {
        float p = __builtin_amdgcn_exp2f(fmaf(sacc[ns][r], kExp, -kOff));
        if (diag) {
          int qg = qbase + gq * 4 + r;
          int kg = k0 + h2 * 32 + ns * 16 + lo;
          if (kg > qg) p = 0.f;
        }
        ps[(gq * 4 + r) * 40 + ns * 16 + lo] = (u16)(__float_as_uint(p) >> 16);
      }
  };
  auto pv_phase = [&](f32x4 (&oacc)[4], f32x4& l_acc, const u16* ps,
                      const u16* Vc) {
    short8 pf = *(const short8*)&ps[lo * 40 + gq * 8];   // q=lo, k=gq*8+j
    int pc = ((h2 * 4 + gq) ^ lo7) * 8;                  // keys h2*32+gq*8+j
#pragma unroll
    for (int ds = 0; ds < 4; ++ds) {
      short8 vf = *(const short8*)&Vc[(ds * 16 + lo) * 64 + pc];
      oacc[ds] = __builtin_amdgcn_mfma_f32_16x16x32_bf16(
          pf, vf, oacc[ds], 0, 0, 0);
    }
    l_acc = __builtin_amdgcn_mfma_f32_16x16x32_bf16(pf, ones, l_acc, 0, 0, 0);
  };

  // stage tile t into buffer bu: each of 8 waves stages one 8-row segment
  auto stage_kv = [&](int t, int bu) {
    async16(&Ks[bu][w * 512],
            &KVb[(size_t)(b * 2048 + t * 64 + w * 8 + lrow) * 64 + swz8]);
    async16(&Vt[bu][w * 512],
            &VTb[((size_t)b * 64 + w * 8 + lrow) * 2048 + t * 64 + swz8]);
  };

  u16* ps_hi = &Ps[w][0][0][0];
  u16* ps_lo = &Ps[w][1][0][0];

  int nst = hi + 1;   // staged tiles: keys 0 .. hi*64+63
  stage_kv(0, 0);
  for (int t = 0; t < nst; ++t) {
    int cur = t & 1;
    __syncthreads();                 // cur ready; nxt free (all waves past t-1)
    if (t + 1 < nst) stage_kv(t + 1, cur ^ 1);
    int k0 = t * 64;
    bool lo_on = (t <= a);

    f32x4 sacc_hi[2], sacc_lo[2];
#pragma unroll
    for (int ns = 0; ns < 2; ++ns) { sacc_hi[ns] = zz; sacc_lo[ns] = zz; }

    qk_phase(qf_hi, sacc_hi, Ks[cur]);
    if (lo_on) qk_phase(qf_lo, sacc_lo, Ks[cur]);
    sm_phase(sacc_hi, qb_hi, t == hi, k0, ps_hi);
    if (lo_on) sm_phase(sacc_lo, qb_lo, t == a, k0, ps_lo);
    __threadfence_block();   // wave-private Ps: lgkm wait, no block barrier
    pv_phase(oacc_hi, l_hi, ps_hi, Vt[cur]);
    if (lo_on) pv_phase(oacc_lo, l_lo, ps_lo, Vt[cur]);
  }

  // epilogue: combine key-half partials (waves w and w+4), normalize, store.
  __syncthreads();                   // all PV done; Ks/Vt free as f32 scratch
  float* oscr = (qc < 2) ? (float*)&Ks[0][0] : (float*)&Vt[0][0];
  float* lscr = (float*)&Ps[0][0][0][0];
  int ob = ((qc & 1) * 2) * 1024;    // strip 0 region; strip 1 at +1024
  int lb = (qc * 2) * 256;
  if (h2 == 1) {                     // upper half publishes partials
#pragma unroll
    for (int ds = 0; ds < 4; ++ds)
#pragma unroll
      for (int r = 0; r < 4; ++r) {
        oscr[ob + lane * 16 + ds * 4 + r]        = oacc_hi[ds][r];
        oscr[ob + 1024 + lane * 16 + ds * 4 + r] = oacc_lo[ds][r];
      }
#pragma unroll
    for (int r = 0; r < 4; ++r) {
      lscr[lb + lane * 4 + r]       = l_hi[r];
      lscr[lb + 256 + lane * 4 + r] = l_lo[r];
    }
  }
  __syncthreads();
  if (h2 == 0) {                     // lower half combines + stores
#pragma unroll
    for (int ds = 0; ds < 4; ++ds)
#pragma unroll
      for (int r = 0; r < 4; ++r) {
        oacc_hi[ds][r] += oscr[ob + lane * 16 + ds * 4 + r];
        oacc_lo[ds][r] += oscr[ob + 1024 + lane * 16 + ds * 4 + r];
      }
#pragma unroll
    for (int r = 0; r < 4; ++r) {
      l_hi[r] += lscr[lb + lane * 4 + r];
      l_lo[r] += lscr[lb + 256 + lane * 4 + r];
    }
#pragma unroll
    for (int r = 0; r < 4; ++r) {
      float inv_lo = 1.0f / l_lo[r];
      float inv_hi = 1.0f / l_hi[r];
      int row_lo = b * 2048 + qb_lo + gq * 4 + r;
      int row_hi = b * 2048 + qb_hi + gq * 4 + r;
#pragma unroll
      for (int ds = 0; ds < 4; ++ds) {
        AOb[row_lo * 1024 + h * 64 + ds * 16 + lo] = f32_to_bf16(oacc_lo[ds][r] * inv_lo);
        AOb[row_hi * 1024 + h * 64 + ds * 16 + lo] = f32_to_bf16(oacc_hi[ds][r] * inv_hi);
      }
    }
  }
}

// ---------------------------------------------------------------------------
// Kernel 4: output projection with fp32 bias, fp32 output.  Linear grid 512,
// same XCD-aware m-clustered swizzle as qkv (nb = j>>3 in 0..7).
// ---------------------------------------------------------------------------
__global__ void __launch_bounds__(256) out_gemm(
    const u16* __restrict__ A, const u16* __restrict__ WoT,
    const float* __restrict__ bias, float* __restrict__ C) {
  __shared__ u16 As[2 * 64 * 64];
  __shared__ u16 Bs[2 * 128 * 64];
  int tid = threadIdx.x, lane = tid & 63, w = tid >> 6;
  int wr = w >> 1, wc = w & 1, g = lane >> 4, lo = lane & 15;
  int id = blockIdx.x;
  int xcd = id & 7, j = id >> 3;
  int m0 = (xcd * 8 + (j & 7)) * 64;
  int nb = j >> 3;                          // 0..7
  const u16* BT = WoT + (size_t)nb * 128 * 1024;
  f32x4 acc[2][4];
  f32x4 zz = {0.f, 0.f, 0.f, 0.f};
#pragma unroll
  for (int i = 0; i < 2; ++i)
#pragma unroll
    for (int jj = 0; jj < 4; ++jj) acc[i][jj] = zz;
  gemm_core_64x128_db(A, BT, m0, 1024, acc, As, Bs, lane, w, wr, wc, g, lo);
#pragma unroll
  for (int mi = 0; mi < 2; ++mi)
#pragma unroll
    for (int ni = 0; ni < 4; ++ni)
#pragma unroll
      for (int r = 0; r < 4; ++r) {
        int row = m0 + wr * 32 + mi * 16 + g * 4 + r;
        int col = nb * 128 + wc * 64 + ni * 16 + lo;
        C[row * 1024 + col] = acc[mi][ni][r] + bias[col];
      }
}

// ---------------------------------------------------------------------------
extern "C" void kernel_launch(void* const* d_in, const int* in_sizes, int n_in,
                              void* d_out, int out_size, void* d_ws, size_t ws_size,
                              hipStream_t stream) {
  const float* x  = (const float*)d_in[0];
  const float* Wq = (const float*)d_in[1];
  const float* Wk = (const float*)d_in[2];
  const float* Wv = (const float*)d_in[3];
  const float* Wo = (const float*)d_in[4];
  const float* bo = (const float*)d_in[5];
  float* out = (float*)d_out;

  // bf16 Q scratch lives in d_out (fp32 16.8 MB; Q needs 8 MB, dead before
  // out_gemm overwrites).  ws: AOb | KVb | VTb | Xb | WqT | WoT | WkvT ~21 MB
  u16* ws   = (u16*)d_ws;
  u16* AOb  = ws;                    // 4096*1024
  u16* KVb  = AOb + 4194304;         // 4096*64   (K only, compact)
  u16* VTb  = KVb + 262144;          // 2*64*2048 (V transposed)
  u16* Xb   = VTb + 262144;          // 4096*1024
  u16* WqT  = Xb + 4194304;          // 1024*1024
  u16* WoT  = WqT + 1048576;         // 1024*1024
  u16* WkvT = WoT + 1048576;         // 128*1024
  u16* Qb   = (u16*)d_out;           // 4096*1024 bf16 (scratch phase)

  prep_kernel<<<2592, 256, 0, stream>>>(x, Wq, Wk, Wv, Wo, Xb, WqT, WkvT, WoT);
  qkv_gemm<<<576, 256, 0, stream>>>(Xb, WqT, WkvT, Qb, KVb, VTb);
  attn_kernel<<<dim3(16, 16, 2), 512, 0, stream>>>(Qb, KVb, VTb, AOb);
  out_gemm<<<512, 256, 0, stream>>>(AOb, WoT, bo, out);
}